// Round 1
// baseline (86613.275 us; speedup 1.0000x reference)
//
#include <hip/hip_runtime.h>
#include <cmath>
#include <cstdint>

typedef unsigned long long u64;
typedef uint16_t u16;

#define NB 16
#define NT 500
#define NINPUT 1024
#define NN 4096
#define NWORDS 64   // NN/64
#define FWORDS 16   // NINPUT/64

__device__ __forceinline__ int rfl(int x){ return __builtin_amdgcn_readfirstlane(x); }

// Build input-spike bitmasks: one bit per (b,t,n_in), word-aligned with flat index.
__global__ __launch_bounds__(256) void k_inmask(const float* __restrict__ in, u64* __restrict__ inmask){
  int idx = blockIdx.x * 256 + threadIdx.x;
  u64 bal = __ballot(in[idx] > 0.0f);
  if ((threadIdx.x & 63) == 0) inmask[idx >> 6] = bal;
}

// Zero state, zero t=0 recurrent mask, build excitatory word-mask from cell types.
__global__ __launch_bounds__(256) void k_init(float* __restrict__ st, u64* __restrict__ rmask0,
                                              u64* __restrict__ excw, const int* __restrict__ ctype){
  int idx = blockIdx.x * 256 + threadIdx.x;   // 0..NB*NN-1
#pragma unroll
  for (int a = 0; a < 5; ++a) st[(size_t)a * NB * NN + idx] = 0.0f;
  if (idx < NB * NWORDS) rmask0[idx] = 0ull;
  if (idx < NN){
    u64 bal = __ballot(ctype[idx] == 0);
    if ((threadIdx.x & 63) == 0) excw[idx >> 6] = bal;
  }
}

// One simulation step. Block = 4 batches (one wave each) x 64 columns.
__global__ __launch_bounds__(256) void k_step(
    const float* __restrict__ W, const float* __restrict__ Wff,
    const u64* __restrict__ excw, const u64* __restrict__ inmask,
    const u64* __restrict__ rcur, u64* __restrict__ rnxt,
    float* __restrict__ v, float* __restrict__ I0, float* __restrict__ I1,
    float* __restrict__ Iff, float* __restrict__ refc, float* __restrict__ out,
    int t, float a0, float a1, float aff, float beta, float omb)
{
  const int lane = threadIdx.x & 63;
  const int wv   = threadIdx.x >> 6;                  // local batch 0..3
  const int bk   = blockIdx.x;
  // XCD-aware: xcd = bk&7 (round-robin dispatch), so XCD x owns columns [x*512, x*512+512)
  const int chunk = (bk & 7) * 8 + ((bk >> 3) & 7);   // 0..63
  const int b     = (bk >> 6) * 4 + wv;               // 0..15
  const int m     = chunk * 64 + lane;                // 0..4095

  __shared__ __align__(16) u16 lst[4][5120];
  u16* Lb = lst[wv];

  u64 bits = rcur[b * NWORDS + lane];
  u64 ew   = excw[lane];
  u64 be = bits & ew;
  u64 bi = bits & ~ew;

  int tot_e, tot_i, tot_f;
  { // excitatory list (ascending n): word-major, bit-minor => ascending
    int c = __popcll(be), p = c;
    for (int d = 1; d < 64; d <<= 1){ int o = __shfl_up(p, d, 64); if (lane >= d) p += o; }
    int base = p - c;
    tot_e = __shfl(p, 63, 64);
    u64 x = be; int k = base;
    while (x){ int j = __builtin_ctzll(x); x &= x - 1; Lb[k++] = (u16)((lane << 6) | j); }
  }
  { // inhibitory list
    int c = __popcll(bi), p = c;
    for (int d = 1; d < 64; d <<= 1){ int o = __shfl_up(p, d, 64); if (lane >= d) p += o; }
    int base = tot_e + (p - c);
    tot_i = __shfl(p, 63, 64);
    u64 x = bi; int k = base;
    while (x){ int j = __builtin_ctzll(x); x &= x - 1; Lb[k++] = (u16)((lane << 6) | j); }
  }
  { // feed-forward input list
    u64 bf = (lane < FWORDS) ? inmask[((size_t)b * NT + t) * FWORDS + lane] : 0ull;
    int c = __popcll(bf), p = c;
    for (int d = 1; d < 64; d <<= 1){ int o = __shfl_up(p, d, 64); if (lane >= d) p += o; }
    int base = 4096 + (p - c);
    tot_f = __shfl(p, 63, 64);
    u64 x = bf; int k = base;
    while (x){ int j = __builtin_ctzll(x); x &= x - 1; Lb[k++] = (u16)((lane << 6) | j); }
  }
  // Lists are wave-private; same-wave LDS RAW handled by compiler waitcnts.

  // Sequential ascending-n fp32 chains (bitwise order == reference contraction).
  float de = 0.0f, di = 0.0f, df = 0.0f;
  {
    int i = 0;
    for (; i + 4 <= tot_e; i += 4){
      int n0 = rfl(Lb[i]), n1 = rfl(Lb[i+1]), n2 = rfl(Lb[i+2]), n3 = rfl(Lb[i+3]);
      const float* p0 = W + ((size_t)n0 << 12);
      const float* p1 = W + ((size_t)n1 << 12);
      const float* p2 = W + ((size_t)n2 << 12);
      const float* p3 = W + ((size_t)n3 << 12);
      float w0 = p0[m], w1 = p1[m], w2 = p2[m], w3 = p3[m];
      de = __fadd_rn(__fadd_rn(__fadd_rn(__fadd_rn(de, w0), w1), w2), w3);
    }
    for (; i < tot_e; ++i){
      int n = rfl(Lb[i]);
      de = __fadd_rn(de, (W + ((size_t)n << 12))[m]);
    }
  }
  {
    int i = 0;
    for (; i + 4 <= tot_i; i += 4){
      int n0 = rfl(Lb[tot_e+i]), n1 = rfl(Lb[tot_e+i+1]), n2 = rfl(Lb[tot_e+i+2]), n3 = rfl(Lb[tot_e+i+3]);
      const float* p0 = W + ((size_t)n0 << 12);
      const float* p1 = W + ((size_t)n1 << 12);
      const float* p2 = W + ((size_t)n2 << 12);
      const float* p3 = W + ((size_t)n3 << 12);
      float w0 = p0[m], w1 = p1[m], w2 = p2[m], w3 = p3[m];
      di = __fadd_rn(__fadd_rn(__fadd_rn(__fadd_rn(di, w0), w1), w2), w3);
    }
    for (; i < tot_i; ++i){
      int n = rfl(Lb[tot_e + i]);
      di = __fadd_rn(di, (W + ((size_t)n << 12))[m]);
    }
  }
  {
    int i = 0;
    for (; i + 4 <= tot_f; i += 4){
      int n0 = rfl(Lb[4096+i]), n1 = rfl(Lb[4096+i+1]), n2 = rfl(Lb[4096+i+2]), n3 = rfl(Lb[4096+i+3]);
      const float* p0 = Wff + ((size_t)n0 << 12);
      const float* p1 = Wff + ((size_t)n1 << 12);
      const float* p2 = Wff + ((size_t)n2 << 12);
      const float* p3 = Wff + ((size_t)n3 << 12);
      float w0 = p0[m], w1 = p1[m], w2 = p2[m], w3 = p3[m];
      df = __fadd_rn(__fadd_rn(__fadd_rn(__fadd_rn(df, w0), w1), w2), w3);
    }
    for (; i < tot_f; ++i){
      int n = rfl(Lb[4096 + i]);
      df = __fadd_rn(df, (Wff + ((size_t)n << 12))[m]);
    }
  }

  const int sidx = b * NN + m;
  // I = alpha*I + drive   (separate mul/add roundings; inh drive = -(sum of +W), bitwise == sum of -W)
  float i0 = __fadd_rn(__fmul_rn(a0, I0[sidx]), de);
  float i1 = __fadd_rn(__fmul_rn(a1, I1[sidx]), -di);
  float ff = __fadd_rn(__fmul_rn(aff, Iff[sidx]), df);
  float itot = __fadd_rn(__fadd_rn(i0, i1), ff);
  float rv = refc[sidx];
  float vo = v[sidx];
  float vn = (rv <= 0.0f) ? __fadd_rn(__fmul_rn(beta, vo), __fmul_rn(omb, itot)) : 0.0f;
  bool s = vn > 1.0f;                 // == (v_new - 1 > 0) exactly (monotone/exact)
  refc[sidx] = s ? 2.0f : fmaxf(rv - 1.0f, 0.0f);
  v[sidx]    = s ? 0.0f : vn;
  I0[sidx] = i0; I1[sidx] = i1; Iff[sidx] = ff;
  out[(size_t)b * NT * NN + (size_t)t * NN + m] = s ? 1.0f : 0.0f;

  u64 bal = __ballot(s);              // wave covers m = chunk*64 .. +63 -> word 'chunk'
  if (lane == 0) rnxt[b * NWORDS + chunk] = bal;
}

extern "C" void kernel_launch(void* const* d_in, const int* in_sizes, int n_in,
                              void* d_out, int out_size, void* d_ws, size_t ws_size,
                              hipStream_t stream)
{
  const float* in_sp = (const float*)d_in[0];   // [16,500,1024]
  const float* W     = (const float*)d_in[1];   // [4096,4096]
  const float* Wff   = (const float*)d_in[2];   // [1024,4096]
  const int*   ctype = (const int*)d_in[3];     // [4096]
  float* out = (float*)d_out;

  char* ws = (char*)d_ws;
  float* st = (float*)ws;                               // v,I0,I1,Iff,ref : 5*NB*NN f32
  size_t off = (size_t)5 * NB * NN * sizeof(float);
  u64* rm0    = (u64*)(ws + off); off += (size_t)NB * NWORDS * 8;
  u64* rm1    = (u64*)(ws + off); off += (size_t)NB * NWORDS * 8;
  u64* excw   = (u64*)(ws + off); off += (size_t)NWORDS * 8;
  u64* inmask = (u64*)(ws + off); off += (size_t)NB * NT * FWORDS * 8;

  float* v   = st;
  float* I0  = st + (size_t)1 * NB * NN;
  float* I1  = st + (size_t)2 * NB * NN;
  float* Ifp = st + (size_t)3 * NB * NN;
  float* rfp = st + (size_t)4 * NB * NN;

  // Constants, matching numpy semantics:
  //   alpha = np.exp(np.float32(-1/tau))  -> f32 args, value via correctly-rounded double exp
  //   beta, alpha_ff = float32(np.exp(double))
  float af  = -1.0f / 5.0f;
  float bf  = -1.0f / 10.0f;
  float a0  = (float)std::exp((double)af);
  float a1  = (float)std::exp((double)bf);
  float aff = (float)std::exp(-1.0 / 5.0);
  float beta = (float)std::exp(-1.0 / 20.0);
  float omb  = 1.0f - beta;   // exact (Sterbenz)

  k_inmask<<<(NB * NT * NINPUT) / 256, 256, 0, stream>>>(in_sp, inmask);
  k_init<<<(NB * NN) / 256, 256, 0, stream>>>(st, rm0, excw, ctype);

  for (int t = 0; t < NT; ++t){
    const u64* rc = (t & 1) ? rm1 : rm0;
    u64*       rn = (t & 1) ? rm0 : rm1;
    k_step<<<256, 256, 0, stream>>>(W, Wff, excw, inmask, rc, rn,
                                    v, I0, I1, Ifp, rfp, out,
                                    t, a0, a1, aff, beta, omb);
  }
}

// Round 2
// 18070.483 us; speedup vs baseline: 4.7931x; 4.7931x over previous
//
#include <hip/hip_runtime.h>
#include <cmath>
#include <cstdint>

typedef unsigned long long u64;
typedef uint16_t u16;
typedef uint32_t u32;

#define NB 16
#define NT 500
#define NINPUT 1024
#define NN 4096
#define NWORDS 64   // NN/64
#define FWORDS 16   // NINPUT/64

// Per-wave u16 index-list regions in LDS (16B-aligned starts, room for full
// 32-wide tail-group reads past cnt):
//   E: exc rows (<=3276)  at [0,    3328)
//   I: inh rows (<=820)   at [3328, 4192)
//   F: ff  rows (<=1024)  at [4192, 5216)
#define E_OFF 0
#define I_OFF 3328
#define F_OFF 4192
#define L_TOT 5216

__global__ __launch_bounds__(256) void k_inmask(const float* __restrict__ in, u64* __restrict__ inmask){
  int idx = blockIdx.x * 256 + threadIdx.x;
  u64 bal = __ballot(in[idx] > 0.0f);
  if ((threadIdx.x & 63) == 0) inmask[idx >> 6] = bal;
}

__global__ __launch_bounds__(256) void k_init(float* __restrict__ st, u64* __restrict__ rmask0,
                                              u64* __restrict__ excw, const int* __restrict__ ctype){
  int idx = blockIdx.x * 256 + threadIdx.x;   // 0..NB*NN-1
#pragma unroll
  for (int a = 0; a < 5; ++a) st[(size_t)a * NB * NN + idx] = 0.0f;
  if (idx < NB * NWORDS) rmask0[idx] = 0ull;
  if (idx < NN){
    u64 bal = __ballot(ctype[idx] == 0);
    if ((threadIdx.x & 63) == 0) excw[idx >> 6] = bal;
  }
}

// Sequential ascending-n fp32 add chain over cnt gathered rows, with 32-row
// groups, double-buffered loads (32-64 outstanding wave-loads for MLP).
// Bitwise identical to a plain ascending loop: only LOAD issue is reordered;
// adds stay in order; predicated tail adds +0.0f (identity: all partials >= +0).
__device__ __forceinline__ float chain_sum(const char* __restrict__ Wc,
                                           const u16* __restrict__ L,
                                           int cnt, u32 m4, u32 rowmask)
{
  float acc = 0.0f;
  if (cnt <= 0) return acc;
  const int nfull = cnt >> 5;
  const int rem   = cnt & 31;
  float wA[32], wB[32], wT[32];

#define LOADF(buf, gb) {                                                    \
    _Pragma("unroll")                                                       \
    for (int q = 0; q < 4; ++q){                                            \
      uint4 pk = *(const uint4*)(L + (gb) + q * 8);                         \
      const u32 wda[4] = {pk.x, pk.y, pk.z, pk.w};                          \
      _Pragma("unroll")                                                     \
      for (int h = 0; h < 4; ++h){                                          \
        const int j0 = q * 8 + h * 2;                                       \
        u32 n0 = wda[h] & 0xFFFFu;                                          \
        u32 n1 = wda[h] >> 16;                                              \
        buf[j0]     = *(const float*)(Wc + ((n0 << 14) + m4));              \
        buf[j0 + 1] = *(const float*)(Wc + ((n1 << 14) + m4));              \
      }                                                                      \
    }                                                                        \
  }

#define ACC32(buf) { _Pragma("unroll") for (int j = 0; j < 32; ++j) acc = __fadd_rn(acc, buf[j]); }

  // Tail group: issue its (predicated, clamped) loads FIRST so the latency
  // hides under the main loop; its adds come last (correct chain order).
  if (rem){
    const int gb = nfull << 5;
#pragma unroll
    for (int q = 0; q < 4; ++q){
      uint4 pk = *(const uint4*)(L + gb + q * 8);
      const u32 wda[4] = {pk.x, pk.y, pk.z, pk.w};
#pragma unroll
      for (int h = 0; h < 4; ++h){
        const int j0 = q * 8 + h * 2;
        u32 n0 = (j0     < rem) ? (wda[h] & 0xFFFFu & rowmask) : 0u;  // invalid -> row 0 (L1-hot)
        u32 n1 = (j0 + 1 < rem) ? ((wda[h] >> 16) & rowmask)   : 0u;
        float v0 = *(const float*)(Wc + ((n0 << 14) + m4));
        float v1 = *(const float*)(Wc + ((n1 << 14) + m4));
        wT[j0]     = (j0     < rem) ? v0 : 0.0f;
        wT[j0 + 1] = (j0 + 1 < rem) ? v1 : 0.0f;
      }
    }
  }

  if (nfull){
    LOADF(wA, 0)
    int g = 0;
    for (; g + 2 <= nfull; g += 2){
      LOADF(wB, (g + 1) << 5)
      ACC32(wA)
      if (g + 2 < nfull) LOADF(wA, (g + 2) << 5)
      ACC32(wB)
    }
    if (nfull & 1) ACC32(wA)
  }
  if (rem) ACC32(wT)

#undef LOADF
#undef ACC32
  return acc;
}

// One simulation step. Block = 4 batches (one wave each) x 64 columns.
__global__ __launch_bounds__(256) void k_step(
    const float* __restrict__ W, const float* __restrict__ Wff,
    const u64* __restrict__ excw, const u64* __restrict__ inmask,
    const u64* __restrict__ rcur, u64* __restrict__ rnxt,
    float* __restrict__ v, float* __restrict__ I0, float* __restrict__ I1,
    float* __restrict__ Iff, float* __restrict__ refc, float* __restrict__ out,
    int t, float a0, float a1, float aff, float beta, float omb)
{
  const int lane = threadIdx.x & 63;
  const int wv   = threadIdx.x >> 6;                  // local batch 0..3
  const int bk   = blockIdx.x;
  // XCD-aware: xcd = bk&7 (round-robin dispatch), so XCD x owns columns [x*512, x*512+512)
  const int chunk = (bk & 7) * 8 + ((bk >> 3) & 7);   // 0..63
  const int b     = (bk >> 6) * 4 + wv;               // 0..15
  const int m     = chunk * 64 + lane;                // 0..4095

  __shared__ __align__(16) u16 lst[4][L_TOT];
  u16* Lb = lst[wv];

  u64 bits = rcur[b * NWORDS + lane];
  u64 ew   = excw[lane];
  u64 be = bits & ew;
  u64 bi = bits & ~ew;

  int tot_e, tot_i, tot_f;
  { // excitatory list (ascending n): word-major, bit-minor => ascending
    int c = __popcll(be), p = c;
    for (int d = 1; d < 64; d <<= 1){ int o = __shfl_up(p, d, 64); if (lane >= d) p += o; }
    int k = E_OFF + (p - c);
    tot_e = __shfl(p, 63, 64);
    u64 x = be;
    while (x){ int j = __builtin_ctzll(x); x &= x - 1; Lb[k++] = (u16)((lane << 6) | j); }
  }
  { // inhibitory list
    int c = __popcll(bi), p = c;
    for (int d = 1; d < 64; d <<= 1){ int o = __shfl_up(p, d, 64); if (lane >= d) p += o; }
    int k = I_OFF + (p - c);
    tot_i = __shfl(p, 63, 64);
    u64 x = bi;
    while (x){ int j = __builtin_ctzll(x); x &= x - 1; Lb[k++] = (u16)((lane << 6) | j); }
  }
  { // feed-forward input list
    u64 bf = (lane < FWORDS) ? inmask[((size_t)b * NT + t) * FWORDS + lane] : 0ull;
    int c = __popcll(bf), p = c;
    for (int d = 1; d < 64; d <<= 1){ int o = __shfl_up(p, d, 64); if (lane >= d) p += o; }
    int k = F_OFF + (p - c);
    tot_f = __shfl(p, 63, 64);
    u64 x = bf;
    while (x){ int j = __builtin_ctzll(x); x &= x - 1; Lb[k++] = (u16)((lane << 6) | j); }
  }
  // Lists are wave-private; compiler inserts lgkmcnt waits for same-wave LDS RAW.

  const char* Wc  = (const char*)W;
  const char* Wfc = (const char*)Wff;
  const u32 m4 = (u32)(m << 2);

  float de = chain_sum(Wc,  Lb + E_OFF, tot_e, m4, 4095u);
  float di = chain_sum(Wc,  Lb + I_OFF, tot_i, m4, 4095u);
  float df = chain_sum(Wfc, Lb + F_OFF, tot_f, m4, 1023u);

  const int sidx = b * NN + m;
  // I = alpha*I + drive  (separate mul/add roundings; -(sum of +W) == sum of -W bitwise)
  float i0 = __fadd_rn(__fmul_rn(a0, I0[sidx]), de);
  float i1 = __fadd_rn(__fmul_rn(a1, I1[sidx]), -di);
  float ff = __fadd_rn(__fmul_rn(aff, Iff[sidx]), df);
  float itot = __fadd_rn(__fadd_rn(i0, i1), ff);
  float rv = refc[sidx];
  float vo = v[sidx];
  float vn = (rv <= 0.0f) ? __fadd_rn(__fmul_rn(beta, vo), __fmul_rn(omb, itot)) : 0.0f;
  bool s = vn > 1.0f;                 // == (v_new - 1 > 0) exactly
  refc[sidx] = s ? 2.0f : fmaxf(rv - 1.0f, 0.0f);
  v[sidx]    = s ? 0.0f : vn;
  I0[sidx] = i0; I1[sidx] = i1; Iff[sidx] = ff;
  out[(size_t)b * NT * NN + (size_t)t * NN + m] = s ? 1.0f : 0.0f;

  u64 bal = __ballot(s);              // wave covers m = chunk*64 .. +63 -> word 'chunk'
  if (lane == 0) rnxt[b * NWORDS + chunk] = bal;
}

extern "C" void kernel_launch(void* const* d_in, const int* in_sizes, int n_in,
                              void* d_out, int out_size, void* d_ws, size_t ws_size,
                              hipStream_t stream)
{
  const float* in_sp = (const float*)d_in[0];   // [16,500,1024]
  const float* W     = (const float*)d_in[1];   // [4096,4096]
  const float* Wff   = (const float*)d_in[2];   // [1024,4096]
  const int*   ctype = (const int*)d_in[3];     // [4096]
  float* out = (float*)d_out;

  char* ws = (char*)d_ws;
  float* st = (float*)ws;                               // v,I0,I1,Iff,ref : 5*NB*NN f32
  size_t off = (size_t)5 * NB * NN * sizeof(float);
  u64* rm0    = (u64*)(ws + off); off += (size_t)NB * NWORDS * 8;
  u64* rm1    = (u64*)(ws + off); off += (size_t)NB * NWORDS * 8;
  u64* excw   = (u64*)(ws + off); off += (size_t)NWORDS * 8;
  u64* inmask = (u64*)(ws + off); off += (size_t)NB * NT * FWORDS * 8;

  float* v   = st;
  float* I0  = st + (size_t)1 * NB * NN;
  float* I1  = st + (size_t)2 * NB * NN;
  float* Ifp = st + (size_t)3 * NB * NN;
  float* rfp = st + (size_t)4 * NB * NN;

  // Constants matching numpy semantics (validated bit-exact in round 1):
  float af  = -1.0f / 5.0f;
  float bf  = -1.0f / 10.0f;
  float a0  = (float)std::exp((double)af);
  float a1  = (float)std::exp((double)bf);
  float aff = (float)std::exp(-1.0 / 5.0);
  float beta = (float)std::exp(-1.0 / 20.0);
  float omb  = 1.0f - beta;   // exact (Sterbenz)

  k_inmask<<<(NB * NT * NINPUT) / 256, 256, 0, stream>>>(in_sp, inmask);
  k_init<<<(NB * NN) / 256, 256, 0, stream>>>(st, rm0, excw, ctype);

  for (int t = 0; t < NT; ++t){
    const u64* rc = (t & 1) ? rm1 : rm0;
    u64*       rn = (t & 1) ? rm0 : rm1;
    k_step<<<256, 256, 0, stream>>>(W, Wff, excw, inmask, rc, rn,
                                    v, I0, I1, Ifp, rfp, out,
                                    t, a0, a1, aff, beta, omb);
  }
}